// Round 1
// baseline (451.649 us; speedup 1.0000x reference)
//
#include <hip/hip_runtime.h>
#include <hip/hip_bf16.h>
#include <math.h>

#define HIDDEN 1024
#define NCLS 64

// ---------------- edge dtype detection ----------------
// Reference uses int64 edge_index; harness docs say ints arrive as int32.
// Detect on device: if the buffer is int64 (little-endian), every odd int32
// word (high word) is 0 since indices < 50000. Random int32 indices make
// 32K consecutive odd words all-zero essentially impossible.
__global__ void detect_i64_kernel(const int* __restrict__ ei, int* __restrict__ flag) {
    __shared__ int any_nonzero;
    if (threadIdx.x == 0) any_nonzero = 0;
    __syncthreads();
    int found = 0;
    for (int i = 1 + 2 * (int)threadIdx.x; i < 65536; i += 512) {
        if (ei[i] != 0) found = 1;
    }
    if (found) atomicOr(&any_nonzero, 1);
    __syncthreads();
    if (threadIdx.x == 0) *flag = (any_nonzero == 0) ? 1 : 0;  // 1 => int64
}

__device__ __forceinline__ int load_src(const int* ei, int E, int e, int is64) {
    return is64 ? ei[2 * e] : ei[e];
}
__device__ __forceinline__ int load_dst(const int* ei, int E, int e, int is64) {
    return is64 ? ei[2 * (E + e)] : ei[E + e];
}

// ---------------- degree count ----------------
__global__ void count_kernel(const int* __restrict__ ei, int* __restrict__ cnt,
                             const int* __restrict__ flag, int E) {
    int is64 = *flag;
    int e = blockIdx.x * blockDim.x + threadIdx.x;
    if (e < E) atomicAdd(&cnt[load_dst(ei, E, e, is64)], 1);
}

__global__ void dis_kernel(const int* __restrict__ cnt, float* __restrict__ dis, int n) {
    int i = blockIdx.x * blockDim.x + threadIdx.x;
    if (i < n) dis[i] = rsqrtf((float)cnt[i] + 1.0f);  // +1 self-loop, always > 0
}

// ---------------- prefix sum (3 phases) ----------------
__global__ void block_reduce_kernel(const int* __restrict__ cnt, int* __restrict__ blk, int n) {
    int tid = threadIdx.x;
    int i = blockIdx.x * 256 + tid;
    int v = (i < n) ? cnt[i] : 0;
    #pragma unroll
    for (int off = 32; off > 0; off >>= 1) v += __shfl_xor(v, off);
    __shared__ int w[4];
    if ((tid & 63) == 0) w[tid >> 6] = v;
    __syncthreads();
    if (tid == 0) blk[blockIdx.x] = w[0] + w[1] + w[2] + w[3];
}

__global__ void scan_blk_kernel(int* __restrict__ blk, int nb) {
    __shared__ int s[256];
    int tid = threadIdx.x;
    int v = (tid < nb) ? blk[tid] : 0;
    s[tid] = v;
    __syncthreads();
    for (int off = 1; off < 256; off <<= 1) {
        int t = (tid >= off) ? s[tid - off] : 0;
        __syncthreads();
        s[tid] += t;
        __syncthreads();
    }
    if (tid < nb) blk[tid] = s[tid] - v;  // exclusive
}

__global__ void scan_write_kernel(const int* __restrict__ cnt, const int* __restrict__ blk,
                                  int* __restrict__ row_ptr, int* __restrict__ cursor, int n) {
    __shared__ int s[256];
    int tid = threadIdx.x;
    int i = blockIdx.x * 256 + tid;
    int v = (i < n) ? cnt[i] : 0;
    s[tid] = v;
    __syncthreads();
    for (int off = 1; off < 256; off <<= 1) {
        int t = (tid >= off) ? s[tid - off] : 0;
        __syncthreads();
        s[tid] += t;
        __syncthreads();
    }
    int excl = s[tid] - v + blk[blockIdx.x];
    if (i < n) {
        row_ptr[i] = excl;
        cursor[i] = excl;
        if (i == n - 1) row_ptr[n] = excl + v;  // == E
    }
}

__global__ void csr_fill_kernel(const int* __restrict__ ei, int* __restrict__ cursor,
                                int* __restrict__ col, const int* __restrict__ flag, int E) {
    int is64 = *flag;
    int e = blockIdx.x * blockDim.x + threadIdx.x;
    if (e < E) {
        int d = load_dst(ei, E, e, is64);
        int slot = atomicAdd(&cursor[d], 1);
        col[slot] = load_src(ei, E, e, is64);
    }
}

// ---------------- GEMM: h = x @ W  (fp32, 64x64 tile, BK=16) ----------------
__global__ __launch_bounds__(256) void gemm_kernel(const float* __restrict__ x,
                                                   const float* __restrict__ W,
                                                   float* __restrict__ h, int M) {
    __shared__ float As[16][64];
    __shared__ float Bs[16][64];
    int tid = threadIdx.x;
    int block_row = blockIdx.x * 64;
    int tx = tid & 15, ty = tid >> 4;
    int lr = tid >> 2;             // A-load row within tile (0..63)
    int lk = (tid & 3) * 4;        // A-load k offset (0,4,8,12)
    int br = tid >> 4;             // B-load row (0..15)
    int bc = (tid & 15) * 4;       // B-load col
    float acc[4][4] = {};
    for (int k0 = 0; k0 < HIDDEN; k0 += 16) {
        float4 av = make_float4(0.f, 0.f, 0.f, 0.f);
        int arow = block_row + lr;
        if (arow < M)
            av = *reinterpret_cast<const float4*>(&x[(size_t)arow * HIDDEN + k0 + lk]);
        As[lk + 0][lr] = av.x;
        As[lk + 1][lr] = av.y;
        As[lk + 2][lr] = av.z;
        As[lk + 3][lr] = av.w;
        float4 bv = *reinterpret_cast<const float4*>(&W[(size_t)(k0 + br) * NCLS + bc]);
        *reinterpret_cast<float4*>(&Bs[br][bc]) = bv;
        __syncthreads();
        #pragma unroll
        for (int kk = 0; kk < 16; ++kk) {
            float4 a = *reinterpret_cast<const float4*>(&As[kk][ty * 4]);
            float4 b = *reinterpret_cast<const float4*>(&Bs[kk][tx * 4]);
            float ar[4] = {a.x, a.y, a.z, a.w};
            float br2[4] = {b.x, b.y, b.z, b.w};
            #pragma unroll
            for (int i2 = 0; i2 < 4; ++i2)
                #pragma unroll
                for (int j = 0; j < 4; ++j)
                    acc[i2][j] += ar[i2] * br2[j];
        }
        __syncthreads();
    }
    #pragma unroll
    for (int i2 = 0; i2 < 4; ++i2) {
        int row = block_row + ty * 4 + i2;
        if (row < M) {
            float4 o = make_float4(acc[i2][0], acc[i2][1], acc[i2][2], acc[i2][3]);
            *reinterpret_cast<float4*>(&h[(size_t)row * NCLS + tx * 4]) = o;
        }
    }
}

// ---------------- aggregation + bias + softmax ----------------
// One 64-lane wave per node; lane c owns class c. Pure gather via CSR.
__global__ __launch_bounds__(256) void aggregate_kernel(const float* __restrict__ h,
                                                        const float* __restrict__ dis,
                                                        const int* __restrict__ row_ptr,
                                                        const int* __restrict__ col,
                                                        const float* __restrict__ bias,
                                                        float* __restrict__ out, int n) {
    int node = blockIdx.x * 4 + ((int)threadIdx.x >> 6);
    int lane = (int)threadIdx.x & 63;
    if (node >= n) return;
    float di = dis[node];
    float acc = h[(size_t)node * NCLS + lane] * di * di;  // self-loop term
    int e0 = row_ptr[node], e1 = row_ptr[node + 1];
    for (int e = e0; e < e1; e += 64) {
        int nrem = e1 - e;
        if (nrem > 64) nrem = 64;
        int sidx = 0;
        float dsv = 0.f;
        if (lane < nrem) {
            sidx = col[e + lane];
            dsv = dis[sidx];
        }
        for (int j = 0; j < nrem; ++j) {
            int sj = __shfl(sidx, j);
            float wj = __shfl(dsv, j) * di;
            acc += h[(size_t)sj * NCLS + lane] * wj;
        }
    }
    acc += bias[lane];
    // softmax across the 64 lanes
    float m = acc;
    #pragma unroll
    for (int off = 32; off > 0; off >>= 1) m = fmaxf(m, __shfl_xor(m, off));
    float ex = __expf(acc - m);
    float sum = ex;
    #pragma unroll
    for (int off = 32; off > 0; off >>= 1) sum += __shfl_xor(sum, off);
    out[(size_t)node * NCLS + lane] = ex / sum;
}

// ---------------- launcher ----------------
extern "C" void kernel_launch(void* const* d_in, const int* in_sizes, int n_in,
                              void* d_out, int out_size, void* d_ws, size_t ws_size,
                              hipStream_t stream) {
    const float* x    = (const float*)d_in[0];
    const int*   ei   = (const int*)d_in[1];
    const float* W    = (const float*)d_in[2];
    const float* bias = (const float*)d_in[3];
    float* out = (float*)d_out;

    const int n = in_sizes[0] / HIDDEN;   // 50000
    const int E = in_sizes[1] / 2;        // 1600000

    char* ws = (char*)d_ws;
    size_t off = 0;
    auto alloc = [&](size_t bytes) -> void* {
        void* p = (void*)(ws + off);
        off = (off + bytes + 255) & ~((size_t)255);
        return p;
    };
    int*   flag    = (int*)alloc(4);
    int*   cnt     = (int*)alloc((size_t)n * 4);
    float* dis     = (float*)alloc((size_t)n * 4);
    int*   row_ptr = (int*)alloc((size_t)(n + 1) * 4);
    int*   cursor  = (int*)alloc((size_t)n * 4);
    int*   blk     = (int*)alloc(1024 * 4);
    int*   col     = (int*)alloc((size_t)E * 4);
    float* h       = (float*)alloc((size_t)n * NCLS * 4);
    (void)ws_size;

    hipMemsetAsync(cnt, 0, (size_t)n * 4, stream);

    detect_i64_kernel<<<1, 256, 0, stream>>>(ei, flag);
    count_kernel<<<(E + 255) / 256, 256, 0, stream>>>(ei, cnt, flag, E);
    dis_kernel<<<(n + 255) / 256, 256, 0, stream>>>(cnt, dis, n);

    int nb = (n + 255) / 256;  // 196 <= 256
    block_reduce_kernel<<<nb, 256, 0, stream>>>(cnt, blk, n);
    scan_blk_kernel<<<1, 256, 0, stream>>>(blk, nb);
    scan_write_kernel<<<nb, 256, 0, stream>>>(cnt, blk, row_ptr, cursor, n);
    csr_fill_kernel<<<(E + 255) / 256, 256, 0, stream>>>(ei, cursor, col, flag, E);

    gemm_kernel<<<(n + 63) / 64, 256, 0, stream>>>(x, W, h, n);
    aggregate_kernel<<<(n + 3) / 4, 256, 0, stream>>>(h, dis, row_ptr, col, bias, out, n);
}

// Round 2
// 440.179 us; speedup vs baseline: 1.0261x; 1.0261x over previous
//
#include <hip/hip_runtime.h>
#include <hip/hip_bf16.h>
#include <math.h>

#define HIDDEN 1024
#define NCLS 64

typedef __attribute__((ext_vector_type(8))) short short8;
typedef __attribute__((ext_vector_type(4))) float f32x4;

__device__ __forceinline__ unsigned short f2bf_rne(float f) {
    unsigned u = __builtin_bit_cast(unsigned, f);
    unsigned r = (u + 0x7FFFu + ((u >> 16) & 1u)) >> 16;
    return (unsigned short)r;
}
__device__ __forceinline__ float bf2f(unsigned short b) {
    unsigned u = ((unsigned)b) << 16;
    return __builtin_bit_cast(float, u);
}

// ---------------- edge dtype detection ----------------
__global__ void detect_i64_kernel(const int* __restrict__ ei, int* __restrict__ flag) {
    __shared__ int any_nonzero;
    if (threadIdx.x == 0) any_nonzero = 0;
    __syncthreads();
    int found = 0;
    for (int i = 1 + 2 * (int)threadIdx.x; i < 65536; i += 512) {
        if (ei[i] != 0) found = 1;
    }
    if (found) atomicOr(&any_nonzero, 1);
    __syncthreads();
    if (threadIdx.x == 0) *flag = (any_nonzero == 0) ? 1 : 0;  // 1 => int64
}

__device__ __forceinline__ int load_src(const int* ei, int E, int e, int is64) {
    return is64 ? ei[2 * e] : ei[e];
}
__device__ __forceinline__ int load_dst(const int* ei, int E, int e, int is64) {
    return is64 ? ei[2 * (E + e)] : ei[E + e];
}

// ---------------- degree count ----------------
__global__ void count_kernel(const int* __restrict__ ei, int* __restrict__ cnt,
                             const int* __restrict__ flag, int E) {
    int is64 = *flag;
    int e = blockIdx.x * blockDim.x + threadIdx.x;
    if (e < E) atomicAdd(&cnt[load_dst(ei, E, e, is64)], 1);
}

__global__ void dis_kernel(const int* __restrict__ cnt, float* __restrict__ dis, int n) {
    int i = blockIdx.x * blockDim.x + threadIdx.x;
    if (i < n) dis[i] = rsqrtf((float)cnt[i] + 1.0f);  // +1 self-loop, always > 0
}

// ---------------- prefix sum (3 phases) ----------------
__global__ void block_reduce_kernel(const int* __restrict__ cnt, int* __restrict__ blk, int n) {
    int tid = threadIdx.x;
    int i = blockIdx.x * 256 + tid;
    int v = (i < n) ? cnt[i] : 0;
    #pragma unroll
    for (int off = 32; off > 0; off >>= 1) v += __shfl_xor(v, off);
    __shared__ int w[4];
    if ((tid & 63) == 0) w[tid >> 6] = v;
    __syncthreads();
    if (tid == 0) blk[blockIdx.x] = w[0] + w[1] + w[2] + w[3];
}

__global__ void scan_blk_kernel(int* __restrict__ blk, int nb) {
    __shared__ int s[256];
    int tid = threadIdx.x;
    int v = (tid < nb) ? blk[tid] : 0;
    s[tid] = v;
    __syncthreads();
    for (int off = 1; off < 256; off <<= 1) {
        int t = (tid >= off) ? s[tid - off] : 0;
        __syncthreads();
        s[tid] += t;
        __syncthreads();
    }
    if (tid < nb) blk[tid] = s[tid] - v;  // exclusive
}

__global__ void scan_write_kernel(const int* __restrict__ cnt, const int* __restrict__ blk,
                                  int* __restrict__ row_ptr, int* __restrict__ cursor, int n) {
    __shared__ int s[256];
    int tid = threadIdx.x;
    int i = blockIdx.x * 256 + tid;
    int v = (i < n) ? cnt[i] : 0;
    s[tid] = v;
    __syncthreads();
    for (int off = 1; off < 256; off <<= 1) {
        int t = (tid >= off) ? s[tid - off] : 0;
        __syncthreads();
        s[tid] += t;
        __syncthreads();
    }
    int excl = s[tid] - v + blk[blockIdx.x];
    if (i < n) {
        row_ptr[i] = excl;
        cursor[i] = excl;
        if (i == n - 1) row_ptr[n] = excl + v;  // == E
    }
}

__global__ void csr_fill_kernel(const int* __restrict__ ei, int* __restrict__ cursor,
                                int* __restrict__ col, const int* __restrict__ flag, int E) {
    int is64 = *flag;
    int e = blockIdx.x * blockDim.x + threadIdx.x;
    if (e < E) {
        int d = load_dst(ei, E, e, is64);
        int slot = atomicAdd(&cursor[d], 1);
        col[slot] = load_src(ei, E, e, is64);
    }
}

// ---------------- W prep: transpose + split into bf16 hi/lo ----------------
// wt_hi/wt_lo layout: [c][k] (c = 0..63, k = 0..1023), k contiguous.
__global__ void wprep_kernel(const float* __restrict__ W,
                             short* __restrict__ wt_hi, short* __restrict__ wt_lo) {
    int idx = blockIdx.x * 256 + threadIdx.x;  // 0..65535
    int c = idx >> 10;
    int k = idx & 1023;
    float f = W[(size_t)k * NCLS + c];
    unsigned short hb = f2bf_rne(f);
    float lo = f - bf2f(hb);
    wt_hi[idx] = (short)hb;
    wt_lo[idx] = (short)f2bf_rne(lo);
}

// ---------------- GEMM via split-bf16 MFMA ----------------
// h = x @ W computed as x_hi@W_hi + x_lo@W_hi + x_hi@W_lo (fp32 accumulate).
// Block = 256 threads = 4 waves; each wave owns 32 rows x 64 cols.
// A fragments loaded straight from global (no LDS); W from L2-resident
// pre-transposed bf16 hi/lo.
__global__ __launch_bounds__(256) void gemm_mfma_kernel(const float* __restrict__ x,
                                                        const short* __restrict__ wt_hi,
                                                        const short* __restrict__ wt_lo,
                                                        float* __restrict__ h, int M) {
    const int tid = threadIdx.x;
    const int wave = tid >> 6;
    const int lane = tid & 63;
    const int l15 = lane & 15;
    const int l4 = lane >> 4;  // 0..3
    const int rbase = blockIdx.x * 128 + wave * 32;

    const int row0 = rbase + l15;
    const int row1 = rbase + 16 + l15;
    const bool v0 = row0 < M;
    const bool v1 = row1 < M;
    const float* xp0 = x + (size_t)row0 * HIDDEN + l4 * 8;
    const float* xp1 = x + (size_t)row1 * HIDDEN + l4 * 8;
    const int bko = l4 * 8;  // k-offset within fragment for B loads

    f32x4 acc[2][4];
    #pragma unroll
    for (int f = 0; f < 2; ++f)
        #pragma unroll
        for (int nf = 0; nf < 4; ++nf)
            acc[f][nf] = (f32x4){0.f, 0.f, 0.f, 0.f};

    for (int k0 = 0; k0 < HIDDEN; k0 += 32) {
        // ---- load + split A fragments ----
        float a0[8], a1[8];
        if (v0) {
            float4 p = *reinterpret_cast<const float4*>(xp0 + k0);
            float4 q = *reinterpret_cast<const float4*>(xp0 + k0 + 4);
            a0[0] = p.x; a0[1] = p.y; a0[2] = p.z; a0[3] = p.w;
            a0[4] = q.x; a0[5] = q.y; a0[6] = q.z; a0[7] = q.w;
        } else {
            #pragma unroll
            for (int j = 0; j < 8; ++j) a0[j] = 0.f;
        }
        if (v1) {
            float4 p = *reinterpret_cast<const float4*>(xp1 + k0);
            float4 q = *reinterpret_cast<const float4*>(xp1 + k0 + 4);
            a1[0] = p.x; a1[1] = p.y; a1[2] = p.z; a1[3] = p.w;
            a1[4] = q.x; a1[5] = q.y; a1[6] = q.z; a1[7] = q.w;
        } else {
            #pragma unroll
            for (int j = 0; j < 8; ++j) a1[j] = 0.f;
        }
        short8 a0h, a0l, a1h, a1l;
        #pragma unroll
        for (int j = 0; j < 8; ++j) {
            unsigned short hb = f2bf_rne(a0[j]);
            a0h[j] = (short)hb;
            a0l[j] = (short)f2bf_rne(a0[j] - bf2f(hb));
            unsigned short hb1 = f2bf_rne(a1[j]);
            a1h[j] = (short)hb1;
            a1l[j] = (short)f2bf_rne(a1[j] - bf2f(hb1));
        }
        // ---- load B fragments (L2-resident) ----
        short8 bh[4], bl[4];
        #pragma unroll
        for (int nf = 0; nf < 4; ++nf) {
            int c = l15 + 16 * nf;
            bh[nf] = *reinterpret_cast<const short8*>(wt_hi + (size_t)c * HIDDEN + k0 + bko);
            bl[nf] = *reinterpret_cast<const short8*>(wt_lo + (size_t)c * HIDDEN + k0 + bko);
        }
        // ---- MFMAs: hi@hi + lo@hi + hi@lo ----
        #pragma unroll
        for (int nf = 0; nf < 4; ++nf) {
            acc[0][nf] = __builtin_amdgcn_mfma_f32_16x16x32_bf16(a0h, bh[nf], acc[0][nf], 0, 0, 0);
            acc[0][nf] = __builtin_amdgcn_mfma_f32_16x16x32_bf16(a0l, bh[nf], acc[0][nf], 0, 0, 0);
            acc[0][nf] = __builtin_amdgcn_mfma_f32_16x16x32_bf16(a0h, bl[nf], acc[0][nf], 0, 0, 0);
            acc[1][nf] = __builtin_amdgcn_mfma_f32_16x16x32_bf16(a1h, bh[nf], acc[1][nf], 0, 0, 0);
            acc[1][nf] = __builtin_amdgcn_mfma_f32_16x16x32_bf16(a1l, bh[nf], acc[1][nf], 0, 0, 0);
            acc[1][nf] = __builtin_amdgcn_mfma_f32_16x16x32_bf16(a1h, bl[nf], acc[1][nf], 0, 0, 0);
        }
    }

    // ---- store: D layout col=lane&15, row=(lane>>4)*4+reg ----
    #pragma unroll
    for (int f = 0; f < 2; ++f) {
        #pragma unroll
        for (int j = 0; j < 4; ++j) {
            int row = rbase + f * 16 + l4 * 4 + j;
            if (row < M) {
                #pragma unroll
                for (int nf = 0; nf < 4; ++nf) {
                    h[(size_t)row * NCLS + l15 + 16 * nf] = acc[f][nf][j];
                }
            }
        }
    }
}

// ---------------- aggregation + bias + softmax ----------------
__global__ __launch_bounds__(256) void aggregate_kernel(const float* __restrict__ h,
                                                        const float* __restrict__ dis,
                                                        const int* __restrict__ row_ptr,
                                                        const int* __restrict__ col,
                                                        const float* __restrict__ bias,
                                                        float* __restrict__ out, int n) {
    int node = blockIdx.x * 4 + ((int)threadIdx.x >> 6);
    int lane = (int)threadIdx.x & 63;
    if (node >= n) return;
    float di = dis[node];
    float acc = h[(size_t)node * NCLS + lane] * di * di;  // self-loop term
    int e0 = row_ptr[node], e1 = row_ptr[node + 1];
    for (int e = e0; e < e1; e += 64) {
        int nrem = e1 - e;
        if (nrem > 64) nrem = 64;
        int sidx = 0;
        float dsv = 0.f;
        if (lane < nrem) {
            sidx = col[e + lane];
            dsv = dis[sidx];
        }
        for (int j = 0; j < nrem; ++j) {
            int sj = __shfl(sidx, j);
            float wj = __shfl(dsv, j) * di;
            acc += h[(size_t)sj * NCLS + lane] * wj;
        }
    }
    acc += bias[lane];
    float m = acc;
    #pragma unroll
    for (int off = 32; off > 0; off >>= 1) m = fmaxf(m, __shfl_xor(m, off));
    float ex = __expf(acc - m);
    float sum = ex;
    #pragma unroll
    for (int off = 32; off > 0; off >>= 1) sum += __shfl_xor(sum, off);
    out[(size_t)node * NCLS + lane] = ex / sum;
}

// ---------------- launcher ----------------
extern "C" void kernel_launch(void* const* d_in, const int* in_sizes, int n_in,
                              void* d_out, int out_size, void* d_ws, size_t ws_size,
                              hipStream_t stream) {
    const float* x    = (const float*)d_in[0];
    const int*   ei   = (const int*)d_in[1];
    const float* W    = (const float*)d_in[2];
    const float* bias = (const float*)d_in[3];
    float* out = (float*)d_out;

    const int n = in_sizes[0] / HIDDEN;   // 50000
    const int E = in_sizes[1] / 2;        // 1600000

    char* ws = (char*)d_ws;
    size_t off = 0;
    auto alloc = [&](size_t bytes) -> void* {
        void* p = (void*)(ws + off);
        off = (off + bytes + 255) & ~((size_t)255);
        return p;
    };
    int*   flag    = (int*)alloc(4);
    int*   cnt     = (int*)alloc((size_t)n * 4);
    float* dis     = (float*)alloc((size_t)n * 4);
    int*   row_ptr = (int*)alloc((size_t)(n + 1) * 4);
    int*   cursor  = (int*)alloc((size_t)n * 4);
    int*   blk     = (int*)alloc(1024 * 4);
    int*   col     = (int*)alloc((size_t)E * 4);
    float* h       = (float*)alloc((size_t)n * NCLS * 4);
    short* wt_hi   = (short*)alloc((size_t)NCLS * HIDDEN * 2);
    short* wt_lo   = (short*)alloc((size_t)NCLS * HIDDEN * 2);
    (void)ws_size;

    hipMemsetAsync(cnt, 0, (size_t)n * 4, stream);

    detect_i64_kernel<<<1, 256, 0, stream>>>(ei, flag);
    count_kernel<<<(E + 255) / 256, 256, 0, stream>>>(ei, cnt, flag, E);
    dis_kernel<<<(n + 255) / 256, 256, 0, stream>>>(cnt, dis, n);

    int nb = (n + 255) / 256;  // 196 <= 256
    block_reduce_kernel<<<nb, 256, 0, stream>>>(cnt, blk, n);
    scan_blk_kernel<<<1, 256, 0, stream>>>(blk, nb);
    scan_write_kernel<<<nb, 256, 0, stream>>>(cnt, blk, row_ptr, cursor, n);
    csr_fill_kernel<<<(E + 255) / 256, 256, 0, stream>>>(ei, cursor, col, flag, E);

    wprep_kernel<<<(NCLS * HIDDEN) / 256, 256, 0, stream>>>(W, wt_hi, wt_lo);
    gemm_mfma_kernel<<<(n + 127) / 128, 256, 0, stream>>>(x, wt_hi, wt_lo, h, n);
    aggregate_kernel<<<(n + 3) / 4, 256, 0, stream>>>(h, dis, row_ptr, col, bias, out, n);
}

// Round 3
// 303.015 us; speedup vs baseline: 1.4905x; 1.4527x over previous
//
#include <hip/hip_runtime.h>
#include <hip/hip_bf16.h>
#include <math.h>

#define HIDDEN 1024
#define NCLS 64
#define NB 196          // node buckets: bucket = dst >> 8 (50000 -> 196)
#define BCAP 10240      // per-bucket capacity (mean 8192, sigma ~90)
#define CHUNK 4096      // edges per block in bucket_kernel

typedef __attribute__((ext_vector_type(8))) short short8;
typedef __attribute__((ext_vector_type(4))) float f32x4;

__device__ __forceinline__ short f2bf(float f) {
    __hip_bfloat16 b = __float2bfloat16(f);
    return __builtin_bit_cast(short, b);
}
__device__ __forceinline__ float bf2f(short s) {
    unsigned u = ((unsigned)(unsigned short)s) << 16;
    return __builtin_bit_cast(float, u);
}

// ---------------- edge dtype detection ----------------
__global__ void detect_i64_kernel(const int* __restrict__ ei, int* __restrict__ flag) {
    __shared__ int any_nonzero;
    if (threadIdx.x == 0) any_nonzero = 0;
    __syncthreads();
    int found = 0;
    for (int i = 1 + 2 * (int)threadIdx.x; i < 65536; i += 512) {
        if (ei[i] != 0) found = 1;
    }
    if (found) atomicOr(&any_nonzero, 1);
    __syncthreads();
    if (threadIdx.x == 0) *flag = (any_nonzero == 0) ? 1 : 0;  // 1 => int64
}

// ---------------- bucket scatter: edges -> (u16 src | u16 dst<<16) per dst-bucket ----------------
__global__ __launch_bounds__(256) void bucket_kernel(const int* __restrict__ ei,
                                                     unsigned* __restrict__ pairs,
                                                     int* __restrict__ bcnt,
                                                     const int* __restrict__ flag, int E) {
    __shared__ int hist[256];
    __shared__ int offs[256];
    __shared__ int cur[256];
    __shared__ int gbase[256];
    __shared__ unsigned stage[CHUNK];
    const int tid = threadIdx.x;
    const int is64 = *flag;
    const int base = blockIdx.x * CHUNK;
    const int cnt_c = min(CHUNK, E - base);

    hist[tid] = 0;
    cur[tid] = 0;
    __syncthreads();

    unsigned pr[16];
    #pragma unroll
    for (int j = 0; j < 16; ++j) {
        int e = base + j * 256 + tid;
        unsigned p = 0xFFFFFFFFu;  // invalid (dst would be >= 50000)
        if (e < E) {
            int s = is64 ? ei[2 * e] : ei[e];
            int d = is64 ? ei[2 * (E + e)] : ei[E + e];
            p = (unsigned)s | ((unsigned)d << 16);
            atomicAdd(&hist[d >> 8], 1);
        }
        pr[j] = p;
    }
    __syncthreads();
    // exclusive scan hist -> offs
    offs[tid] = hist[tid];
    __syncthreads();
    for (int off = 1; off < 256; off <<= 1) {
        int t = (tid >= off) ? offs[tid - off] : 0;
        __syncthreads();
        offs[tid] += t;
        __syncthreads();
    }
    int excl = offs[tid] - hist[tid];
    __syncthreads();
    offs[tid] = excl;
    __syncthreads();
    // scatter into LDS stage (bucket-sorted within chunk)
    #pragma unroll
    for (int j = 0; j < 16; ++j) {
        unsigned p = pr[j];
        if (p != 0xFFFFFFFFu) {
            int b = (int)(p >> 24);
            int pos = offs[b] + atomicAdd(&cur[b], 1);
            stage[pos] = p;
        }
    }
    if (tid < NB && hist[tid] > 0) gbase[tid] = atomicAdd(&bcnt[tid], hist[tid]);
    __syncthreads();
    // coalesced-ish copy out: runs of same bucket are contiguous
    for (int i = tid; i < cnt_c; i += 256) {
        unsigned p = stage[i];
        int b = (int)(p >> 24);
        pairs[(size_t)b * BCAP + gbase[b] + (i - offs[b])] = p;
    }
}

// ---------------- per-bucket degree -> dis (no random atomics) ----------------
__global__ __launch_bounds__(256) void degree_kernel(const unsigned* __restrict__ pairs,
                                                     const int* __restrict__ bcnt,
                                                     float* __restrict__ dis, int n) {
    __shared__ int hist[256];
    const int tid = threadIdx.x;
    const int bucket = blockIdx.x;
    hist[tid] = 0;
    __syncthreads();
    const int cb = bcnt[bucket];
    const unsigned* bp = pairs + (size_t)bucket * BCAP;
    for (int i = tid; i < cb; i += 256) {
        unsigned p = bp[i];
        atomicAdd(&hist[(p >> 16) & 255], 1);
    }
    __syncthreads();
    int node = bucket * 256 + tid;
    if (node < n) dis[node] = rsqrtf((float)hist[tid] + 1.0f);  // +1 self-loop
}

// ---------------- W prep: transpose + split bf16 hi/lo ----------------
__global__ void wprep_kernel(const float* __restrict__ W,
                             short* __restrict__ wt_hi, short* __restrict__ wt_lo) {
    int idx = blockIdx.x * 256 + threadIdx.x;  // 0..65535
    int c = idx >> 10;
    int k = idx & 1023;
    float f = W[(size_t)k * NCLS + c];
    short hb = f2bf(f);
    wt_hi[idx] = hb;
    wt_lo[idx] = f2bf(f - bf2f(hb));
}

// ---------------- GEMM via split-bf16 MFMA: 16 rows/wave, 64 rows/block ----------------
__global__ __launch_bounds__(256) void gemm_mfma_kernel(const float* __restrict__ x,
                                                        const short* __restrict__ wt_hi,
                                                        const short* __restrict__ wt_lo,
                                                        float* __restrict__ h, int M) {
    const int tid = threadIdx.x;
    const int wave = tid >> 6;
    const int lane = tid & 63;
    const int l15 = lane & 15;
    const int l4 = lane >> 4;
    const int rbase = blockIdx.x * 64 + wave * 16;
    const int row = rbase + l15;
    const bool v = row < M;
    const float* xp = x + (size_t)row * HIDDEN + l4 * 8;
    const int bko = l4 * 8;

    f32x4 acc[4];
    #pragma unroll
    for (int nf = 0; nf < 4; ++nf) acc[nf] = (f32x4){0.f, 0.f, 0.f, 0.f};

    #pragma unroll 2
    for (int k0 = 0; k0 < HIDDEN; k0 += 32) {
        float a[8];
        if (v) {
            float4 p = *reinterpret_cast<const float4*>(xp + k0);
            float4 q = *reinterpret_cast<const float4*>(xp + k0 + 4);
            a[0] = p.x; a[1] = p.y; a[2] = p.z; a[3] = p.w;
            a[4] = q.x; a[5] = q.y; a[6] = q.z; a[7] = q.w;
        } else {
            #pragma unroll
            for (int j = 0; j < 8; ++j) a[j] = 0.f;
        }
        short8 ah, al;
        #pragma unroll
        for (int j = 0; j < 8; ++j) {
            short hb = f2bf(a[j]);
            ah[j] = hb;
            al[j] = f2bf(a[j] - bf2f(hb));
        }
        short8 bh[4], bl[4];
        #pragma unroll
        for (int nf = 0; nf < 4; ++nf) {
            int c = l15 + 16 * nf;
            bh[nf] = *reinterpret_cast<const short8*>(wt_hi + (size_t)c * HIDDEN + k0 + bko);
            bl[nf] = *reinterpret_cast<const short8*>(wt_lo + (size_t)c * HIDDEN + k0 + bko);
        }
        #pragma unroll
        for (int nf = 0; nf < 4; ++nf) {
            acc[nf] = __builtin_amdgcn_mfma_f32_16x16x32_bf16(ah, bh[nf], acc[nf], 0, 0, 0);
            acc[nf] = __builtin_amdgcn_mfma_f32_16x16x32_bf16(al, bh[nf], acc[nf], 0, 0, 0);
            acc[nf] = __builtin_amdgcn_mfma_f32_16x16x32_bf16(ah, bl[nf], acc[nf], 0, 0, 0);
        }
    }

    #pragma unroll
    for (int j = 0; j < 4; ++j) {
        int r = rbase + l4 * 4 + j;
        if (r < M) {
            #pragma unroll
            for (int nf = 0; nf < 4; ++nf) {
                h[(size_t)r * NCLS + l15 + 16 * nf] = acc[nf][j];
            }
        }
    }
}

// ---------------- fused: per-32-node-range LDS CSR + gather + bias + softmax ----------------
__global__ __launch_bounds__(256) void agg_kernel(const unsigned* __restrict__ pairs,
                                                  const int* __restrict__ bcnt,
                                                  const float* __restrict__ h,
                                                  const float* __restrict__ dis,
                                                  const float* __restrict__ bias,
                                                  float* __restrict__ out, int n) {
    __shared__ int hist[32];
    __shared__ int offs[33];
    __shared__ int cur[32];
    __shared__ unsigned short ssrc[2048];
    const int tid = threadIdx.x;
    const int bucket = blockIdx.x >> 3;
    const int split = blockIdx.x & 7;
    const int base_node = bucket * 256 + split * 32;
    if (base_node >= n) return;
    if (tid < 32) { hist[tid] = 0; cur[tid] = 0; }
    __syncthreads();
    const int cb = bcnt[bucket];
    const unsigned* bp = pairs + (size_t)bucket * BCAP;
    for (int i = tid; i < cb; i += 256) {
        unsigned p = bp[i];
        int loc = (int)((p >> 16) & 255u);
        if ((loc >> 5) == split) atomicAdd(&hist[loc & 31], 1);
    }
    __syncthreads();
    if (tid == 0) {
        int r = 0;
        #pragma unroll
        for (int k = 0; k < 32; ++k) { offs[k] = r; r += hist[k]; }
        offs[32] = r;
    }
    __syncthreads();
    for (int i = tid; i < cb; i += 256) {
        unsigned p = bp[i];
        int loc = (int)((p >> 16) & 255u);
        if ((loc >> 5) == split) {
            int ln = loc & 31;
            int pos = offs[ln] + atomicAdd(&cur[ln], 1);
            ssrc[pos] = (unsigned short)(p & 0xFFFFu);
        }
    }
    __syncthreads();

    const int wave = tid >> 6;
    const int lane = tid & 63;
    for (int q = 0; q < 8; ++q) {
        int ln = wave * 8 + q;
        int node = base_node + ln;
        if (node >= n) continue;
        float di = dis[node];
        float acc = h[(size_t)node * NCLS + lane] * di * di;  // self-loop
        float acc2 = 0.f;
        int e0 = offs[ln], e1 = offs[ln] + hist[ln];
        for (int e = e0; e < e1; e += 64) {
            int nrem = e1 - e;
            if (nrem > 64) nrem = 64;
            int sidx = 0;
            float dsv = 0.f;
            if (lane < nrem) {
                sidx = ssrc[e + lane];
                dsv = dis[sidx];
            }
            for (int j = 0; j < nrem; j += 2) {
                int sj = __shfl(sidx, j);
                float wj = __shfl(dsv, j) * di;
                acc += h[(size_t)sj * NCLS + lane] * wj;
                if (j + 1 < nrem) {
                    int sk = __shfl(sidx, j + 1);
                    float wk = __shfl(dsv, j + 1) * di;
                    acc2 += h[(size_t)sk * NCLS + lane] * wk;
                }
            }
        }
        acc += acc2 + bias[lane];
        float m = acc;
        #pragma unroll
        for (int off = 32; off > 0; off >>= 1) m = fmaxf(m, __shfl_xor(m, off));
        float ex = __expf(acc - m);
        float sum = ex;
        #pragma unroll
        for (int off = 32; off > 0; off >>= 1) sum += __shfl_xor(sum, off);
        out[(size_t)node * NCLS + lane] = ex / sum;
    }
}

// ---------------- launcher ----------------
extern "C" void kernel_launch(void* const* d_in, const int* in_sizes, int n_in,
                              void* d_out, int out_size, void* d_ws, size_t ws_size,
                              hipStream_t stream) {
    const float* x    = (const float*)d_in[0];
    const int*   ei   = (const int*)d_in[1];
    const float* W    = (const float*)d_in[2];
    const float* bias = (const float*)d_in[3];
    float* out = (float*)d_out;

    const int n = in_sizes[0] / HIDDEN;   // 50000
    const int E = in_sizes[1] / 2;        // 1600000

    char* ws = (char*)d_ws;
    size_t off = 0;
    auto alloc = [&](size_t bytes) -> void* {
        void* p = (void*)(ws + off);
        off = (off + bytes + 255) & ~((size_t)255);
        return p;
    };
    int*      flag  = (int*)alloc(4);
    int*      bcnt  = (int*)alloc((size_t)NB * 4);
    unsigned* pairs = (unsigned*)alloc((size_t)NB * BCAP * 4);
    float*    dis   = (float*)alloc((size_t)n * 4);
    float*    h     = (float*)alloc((size_t)n * NCLS * 4);
    short*    wt_hi = (short*)alloc((size_t)NCLS * HIDDEN * 2);
    short*    wt_lo = (short*)alloc((size_t)NCLS * HIDDEN * 2);
    (void)ws_size;

    hipMemsetAsync(bcnt, 0, (size_t)NB * 4, stream);

    detect_i64_kernel<<<1, 256, 0, stream>>>(ei, flag);
    bucket_kernel<<<(E + CHUNK - 1) / CHUNK, 256, 0, stream>>>(ei, pairs, bcnt, flag, E);
    degree_kernel<<<NB, 256, 0, stream>>>(pairs, bcnt, dis, n);

    wprep_kernel<<<(NCLS * HIDDEN) / 256, 256, 0, stream>>>(W, wt_hi, wt_lo);
    gemm_mfma_kernel<<<(n + 63) / 64, 256, 0, stream>>>(x, wt_hi, wt_lo, h, n);
    agg_kernel<<<NB * 8, 256, 0, stream>>>(pairs, bcnt, h, dis, bias, out, n);
}

// Round 4
// 179.857 us; speedup vs baseline: 2.5112x; 1.6848x over previous
//
#include <hip/hip_runtime.h>
#include <hip/hip_bf16.h>
#include <math.h>

#define HIDDEN 1024
#define NCLS 64
#define NB 196          // node buckets: bucket = dst >> 8 (50000 -> 196)
#define BCAP 10240      // per-bucket capacity (mean 8192)
#define CHUNK 4096      // edges per block in bucket_kernel

typedef __attribute__((ext_vector_type(8))) short short8;
typedef __attribute__((ext_vector_type(4))) float f32x4;

__device__ __forceinline__ short f2bf(float f) {
    __hip_bfloat16 b = __float2bfloat16(f);
    return __builtin_bit_cast(short, b);
}
__device__ __forceinline__ float bf2f(short s) {
    unsigned u = ((unsigned)(unsigned short)s) << 16;
    return __builtin_bit_cast(float, u);
}

// async global->LDS, 16B per lane. LDS dest is wave-uniform base + lane*16.
__device__ __forceinline__ void async_copy16(void* lds, const void* g) {
    __builtin_amdgcn_global_load_lds(
        (const __attribute__((address_space(1))) unsigned int*)g,
        (__attribute__((address_space(3))) unsigned int*)lds, 16, 0, 0);
}

// ---------------- edge dtype detection ----------------
__global__ void detect_i64_kernel(const int* __restrict__ ei, int* __restrict__ flag) {
    __shared__ int any_nonzero;
    if (threadIdx.x == 0) any_nonzero = 0;
    __syncthreads();
    int found = 0;
    for (int i = 1 + 2 * (int)threadIdx.x; i < 65536; i += 512) {
        if (ei[i] != 0) found = 1;
    }
    if (found) atomicOr(&any_nonzero, 1);
    __syncthreads();
    if (threadIdx.x == 0) *flag = (any_nonzero == 0) ? 1 : 0;  // 1 => int64
}

// ---------------- bucket scatter: edges -> (u16 src | u16 dst<<16) per dst-bucket ----------------
__global__ __launch_bounds__(256) void bucket_kernel(const int* __restrict__ ei,
                                                     unsigned* __restrict__ pairs,
                                                     int* __restrict__ bcnt,
                                                     const int* __restrict__ flag, int E) {
    __shared__ int hist[256];
    __shared__ int offs[256];
    __shared__ int cur[256];
    __shared__ int gbase[256];
    __shared__ unsigned stage[CHUNK];
    const int tid = threadIdx.x;
    const int is64 = *flag;
    const int base = blockIdx.x * CHUNK;
    const int cnt_c = min(CHUNK, E - base);

    hist[tid] = 0;
    cur[tid] = 0;
    __syncthreads();

    unsigned pr[16];
    #pragma unroll
    for (int j = 0; j < 16; ++j) {
        int e = base + j * 256 + tid;
        unsigned p = 0xFFFFFFFFu;
        if (e < E) {
            int s = is64 ? ei[2 * e] : ei[e];
            int d = is64 ? ei[2 * (E + e)] : ei[E + e];
            p = (unsigned)s | ((unsigned)d << 16);
            atomicAdd(&hist[d >> 8], 1);
        }
        pr[j] = p;
    }
    __syncthreads();
    offs[tid] = hist[tid];
    __syncthreads();
    for (int off = 1; off < 256; off <<= 1) {
        int t = (tid >= off) ? offs[tid - off] : 0;
        __syncthreads();
        offs[tid] += t;
        __syncthreads();
    }
    int excl = offs[tid] - hist[tid];
    __syncthreads();
    offs[tid] = excl;
    __syncthreads();
    #pragma unroll
    for (int j = 0; j < 16; ++j) {
        unsigned p = pr[j];
        if (p != 0xFFFFFFFFu) {
            int b = (int)(p >> 24);
            int pos = offs[b] + atomicAdd(&cur[b], 1);
            stage[pos] = p;
        }
    }
    if (tid < NB && hist[tid] > 0) gbase[tid] = atomicAdd(&bcnt[tid], hist[tid]);
    __syncthreads();
    for (int i = tid; i < cnt_c; i += 256) {
        unsigned p = stage[i];
        int b = (int)(p >> 24);
        pairs[(size_t)b * BCAP + gbase[b] + (i - offs[b])] = p;
    }
}

// ---------------- per-bucket degree -> dis ----------------
__global__ __launch_bounds__(256) void degree_kernel(const unsigned* __restrict__ pairs,
                                                     const int* __restrict__ bcnt,
                                                     float* __restrict__ dis, int n) {
    __shared__ int hist[256];
    const int tid = threadIdx.x;
    const int bucket = blockIdx.x;
    hist[tid] = 0;
    __syncthreads();
    const int cb = bcnt[bucket];
    const unsigned* bp = pairs + (size_t)bucket * BCAP;
    for (int i = tid; i < cb; i += 256) {
        unsigned p = bp[i];
        atomicAdd(&hist[(p >> 16) & 255], 1);
    }
    __syncthreads();
    int node = bucket * 256 + tid;
    if (node < n) dis[node] = rsqrtf((float)hist[tid] + 1.0f);
}

// ---------------- W prep: transpose + split bf16 hi/lo, layout [c][k] ----------------
__global__ void wprep_kernel(const float* __restrict__ W,
                             short* __restrict__ wt_hi, short* __restrict__ wt_lo) {
    int idx = blockIdx.x * 256 + threadIdx.x;  // 0..65535
    int c = idx >> 10;
    int k = idx & 1023;
    float f = W[(size_t)k * NCLS + c];
    short hb = f2bf(f);
    wt_hi[idx] = hb;
    wt_lo[idx] = f2bf(f - bf2f(hb));
}

// ---------------- GEMM: 64-row tile, K-step 64, global_load_lds staging ----------------
// LDS layout (chunk stride 1040 = 1024 + 16B pad):
//  A: 16 chunks; chunk q rows 4q..4q+3 (fp32, 256B/row), slot j holds global
//     16B-chunk g = j ^ ((row&3)<<2)  [XOR via pre-swizzled global source]
//  Bh/Bl: 8 chunks; chunk q cols 8q..8q+7 (bf16, 128B/row), slot j holds
//     global 16B-chunk g = j ^ (col&7)
__global__ __launch_bounds__(256) void gemm_mfma_kernel(const float* __restrict__ x,
                                                        const short* __restrict__ wt_hi,
                                                        const short* __restrict__ wt_lo,
                                                        float* __restrict__ h, int M) {
    __shared__ char smem[16 * 1040 + 8 * 1040 + 8 * 1040];
    char* As = smem;
    char* Bh = smem + 16 * 1040;
    char* Bl = smem + 24 * 1040;

    const int tid = threadIdx.x;
    const int wave = tid >> 6;
    const int lane = tid & 63;
    const int l15 = lane & 15, l4 = lane >> 4;
    const int row0 = blockIdx.x * 64;

    // --- staging source pointers (pre-swizzled globals) ---
    const float* agp[4];
    #pragma unroll
    for (int i = 0; i < 4; ++i) {
        int rg = row0 + (wave * 4 + i) * 4 + (lane >> 4);
        if (rg > M - 1) rg = M - 1;  // tail clamp: reads valid data, result unstored
        int g = (lane & 15) ^ (((lane >> 4) & 3) << 2);
        agp[i] = x + (size_t)rg * HIDDEN + g * 4;
    }
    const short* bhp[2];
    const short* blp[2];
    #pragma unroll
    for (int i = 0; i < 2; ++i) {
        int c = (wave * 2 + i) * 8 + (lane >> 3);
        int g = (lane & 7) ^ ((lane >> 3) & 7);
        bhp[i] = wt_hi + (size_t)c * HIDDEN + g * 8;
        blp[i] = wt_lo + (size_t)c * HIDDEN + g * 8;
    }

    f32x4 acc[4];
    #pragma unroll
    for (int nf = 0; nf < 4; ++nf) acc[nf] = (f32x4){0.f, 0.f, 0.f, 0.f};

    const int rt = wave * 16 + l15;       // this lane's A row within tile
    const int r3 = rt & 3;
    char* arow = As + (rt >> 2) * 1040 + r3 * 256;

    for (int k0 = 0; k0 < HIDDEN; k0 += 64) {
        // ---- stage (async, coalesced 1KB per inst) ----
        #pragma unroll
        for (int i = 0; i < 4; ++i)
            async_copy16(As + (wave * 4 + i) * 1040, agp[i] + k0);
        #pragma unroll
        for (int i = 0; i < 2; ++i) {
            async_copy16(Bh + (wave * 2 + i) * 1040, bhp[i] + k0);
            async_copy16(Bl + (wave * 2 + i) * 1040, blp[i] + k0);
        }
        __syncthreads();  // drains vmcnt + lgkm

        // ---- compute ----
        #pragma unroll
        for (int kk = 0; kk < 2; ++kk) {
            int js = (kk * 8 + l4 * 2) ^ (r3 << 2);
            f32x4 af0 = *reinterpret_cast<const f32x4*>(arow + js * 16);
            f32x4 af1 = *reinterpret_cast<const f32x4*>(arow + js * 16 + 16);
            short8 ah, al;
            #pragma unroll
            for (int j = 0; j < 4; ++j) {
                short hb = f2bf(af0[j]);
                ah[j] = hb;
                al[j] = f2bf(af0[j] - bf2f(hb));
                short hb2 = f2bf(af1[j]);
                ah[j + 4] = hb2;
                al[j + 4] = f2bf(af1[j] - bf2f(hb2));
            }
            #pragma unroll
            for (int nf = 0; nf < 4; ++nf) {
                int c = l15 + 16 * nf;
                int jb = (kk * 4 + l4) ^ (c & 7);
                size_t boff = (size_t)(c >> 3) * 1040 + (c & 7) * 128 + jb * 16;
                short8 bh = *reinterpret_cast<const short8*>(Bh + boff);
                short8 bl = *reinterpret_cast<const short8*>(Bl + boff);
                acc[nf] = __builtin_amdgcn_mfma_f32_16x16x32_bf16(ah, bh, acc[nf], 0, 0, 0);
                acc[nf] = __builtin_amdgcn_mfma_f32_16x16x32_bf16(al, bh, acc[nf], 0, 0, 0);
                acc[nf] = __builtin_amdgcn_mfma_f32_16x16x32_bf16(ah, bl, acc[nf], 0, 0, 0);
            }
        }
        __syncthreads();
    }

    #pragma unroll
    for (int j = 0; j < 4; ++j) {
        int r = row0 + wave * 16 + l4 * 4 + j;
        if (r < M) {
            #pragma unroll
            for (int nf = 0; nf < 4; ++nf) {
                h[(size_t)r * NCLS + l15 + 16 * nf] = acc[nf][j];
            }
        }
    }
}

// ---------------- fused: LDS edge list (src, dis[src]) + unrolled gather + softmax ----------------
__global__ __launch_bounds__(256) void agg_kernel(const unsigned* __restrict__ pairs,
                                                  const int* __restrict__ bcnt,
                                                  const float* __restrict__ h,
                                                  const float* __restrict__ dis,
                                                  const float* __restrict__ bias,
                                                  float* __restrict__ out, int n) {
    __shared__ int hist[32];
    __shared__ int offs[33];
    __shared__ int cur[32];
    __shared__ unsigned short ssrc[2048];
    __shared__ float swt[2048];
    const int tid = threadIdx.x;
    const int bucket = blockIdx.x >> 3;
    const int split = blockIdx.x & 7;
    const int base_node = bucket * 256 + split * 32;
    if (base_node >= n) return;
    if (tid < 32) { hist[tid] = 0; cur[tid] = 0; }
    __syncthreads();
    const int cb = bcnt[bucket];
    const unsigned* bp = pairs + (size_t)bucket * BCAP;
    for (int i = tid; i < cb; i += 256) {
        unsigned p = bp[i];
        int loc = (int)((p >> 16) & 255u);
        if ((loc >> 5) == split) atomicAdd(&hist[loc & 31], 1);
    }
    __syncthreads();
    if (tid == 0) {
        int r = 0;
        #pragma unroll
        for (int k = 0; k < 32; ++k) { offs[k] = r; r += hist[k]; }
        offs[32] = r;
    }
    __syncthreads();
    for (int i = tid; i < cb; i += 256) {
        unsigned p = bp[i];
        int loc = (int)((p >> 16) & 255u);
        if ((loc >> 5) == split) {
            int ln = loc & 31;
            int pos = offs[ln] + atomicAdd(&cur[ln], 1);
            int s = (int)(p & 0xFFFFu);
            ssrc[pos] = (unsigned short)s;
            swt[pos] = dis[s];
        }
    }
    __syncthreads();

    const int wave = tid >> 6;
    const int lane = tid & 63;
    for (int q = 0; q < 8; ++q) {
        int ln = wave * 8 + q;
        int node = base_node + ln;
        if (node >= n) continue;
        float di = dis[node];
        // acc = di * (di*h_self + sum_e dis[src_e]*h_src) + bias
        float a0 = h[(size_t)node * NCLS + lane] * di;
        float a1 = 0.f, a2 = 0.f, a3 = 0.f;
        int e = offs[ln];
        int len = hist[ln];
        int i = 0;
        for (; i + 4 <= len; i += 4) {
            int s0 = ssrc[e + i], s1 = ssrc[e + i + 1];
            int s2 = ssrc[e + i + 2], s3 = ssrc[e + i + 3];
            float w0 = swt[e + i], w1 = swt[e + i + 1];
            float w2 = swt[e + i + 2], w3 = swt[e + i + 3];
            float g0 = h[(size_t)s0 * NCLS + lane];
            float g1 = h[(size_t)s1 * NCLS + lane];
            float g2 = h[(size_t)s2 * NCLS + lane];
            float g3 = h[(size_t)s3 * NCLS + lane];
            a0 += g0 * w0; a1 += g1 * w1; a2 += g2 * w2; a3 += g3 * w3;
        }
        for (; i < len; ++i)
            a0 += h[(size_t)ssrc[e + i] * NCLS + lane] * swt[e + i];
        float acc = di * ((a0 + a1) + (a2 + a3)) + bias[lane];
        float m = acc;
        #pragma unroll
        for (int off = 32; off > 0; off >>= 1) m = fmaxf(m, __shfl_xor(m, off));
        float ex = __expf(acc - m);
        float sum = ex;
        #pragma unroll
        for (int off = 32; off > 0; off >>= 1) sum += __shfl_xor(sum, off);
        out[(size_t)node * NCLS + lane] = ex / sum;
    }
}

// ---------------- launcher ----------------
extern "C" void kernel_launch(void* const* d_in, const int* in_sizes, int n_in,
                              void* d_out, int out_size, void* d_ws, size_t ws_size,
                              hipStream_t stream) {
    const float* x    = (const float*)d_in[0];
    const int*   ei   = (const int*)d_in[1];
    const float* W    = (const float*)d_in[2];
    const float* bias = (const float*)d_in[3];
    float* out = (float*)d_out;

    const int n = in_sizes[0] / HIDDEN;   // 50000
    const int E = in_sizes[1] / 2;        // 1600000

    char* ws = (char*)d_ws;
    size_t off = 0;
    auto alloc = [&](size_t bytes) -> void* {
        void* p = (void*)(ws + off);
        off = (off + bytes + 255) & ~((size_t)255);
        return p;
    };
    int*      flag  = (int*)alloc(4);
    int*      bcnt  = (int*)alloc((size_t)NB * 4);
    unsigned* pairs = (unsigned*)alloc((size_t)NB * BCAP * 4);
    float*    dis   = (float*)alloc((size_t)n * 4);
    float*    h     = (float*)alloc((size_t)n * NCLS * 4);
    short*    wt_hi = (short*)alloc((size_t)NCLS * HIDDEN * 2);
    short*    wt_lo = (short*)alloc((size_t)NCLS * HIDDEN * 2);
    (void)ws_size;

    hipMemsetAsync(bcnt, 0, (size_t)NB * 4, stream);

    detect_i64_kernel<<<1, 256, 0, stream>>>(ei, flag);
    bucket_kernel<<<(E + CHUNK - 1) / CHUNK, 256, 0, stream>>>(ei, pairs, bcnt, flag, E);
    degree_kernel<<<NB, 256, 0, stream>>>(pairs, bcnt, dis, n);

    wprep_kernel<<<(NCLS * HIDDEN) / 256, 256, 0, stream>>>(W, wt_hi, wt_lo);
    gemm_mfma_kernel<<<(n + 63) / 64, 256, 0, stream>>>(x, wt_hi, wt_lo, h, n);
    agg_kernel<<<NB * 8, 256, 0, stream>>>(pairs, bcnt, h, dis, bias, out, n);
}

// Round 5
// 164.070 us; speedup vs baseline: 2.7528x; 1.0962x over previous
//
#include <hip/hip_runtime.h>
#include <hip/hip_bf16.h>
#include <math.h>

#define HIDDEN 1024
#define NCLS 64
#define NB 196          // node buckets: bucket = dst >> 8 (50000 -> 196)
#define BCAP 10240      // per-bucket capacity (mean 8192)
#define CHUNK 4096      // edges per block in bucket_kernel
#define GCAP 4096       // per-64-node-group edge capacity (mean 2048)

typedef __attribute__((ext_vector_type(8))) short short8;
typedef __attribute__((ext_vector_type(4))) float f32x4;

__device__ __forceinline__ short f2bf(float f) {
    __hip_bfloat16 b = __float2bfloat16(f);
    return __builtin_bit_cast(short, b);
}
__device__ __forceinline__ float bf2f(short s) {
    unsigned u = ((unsigned)(unsigned short)s) << 16;
    return __builtin_bit_cast(float, u);
}

// async global->LDS, 16B per lane. LDS dest is wave-uniform base + lane*16.
__device__ __forceinline__ void async_copy16(void* lds, const void* g) {
    __builtin_amdgcn_global_load_lds(
        (const __attribute__((address_space(1))) unsigned int*)g,
        (__attribute__((address_space(3))) unsigned int*)lds, 16, 0, 0);
}

// ---------------- bucket scatter: edges -> (u16 src | u16 dst<<16) per dst-bucket ----------------
// int64-vs-int32 edge dtype detected per block from its own chunk (high words
// all zero over 1024 samples => int64; random int32 node ids can't do that).
__global__ __launch_bounds__(256) void bucket_kernel(const int* __restrict__ ei,
                                                     unsigned* __restrict__ pairs,
                                                     int* __restrict__ bcnt, int E) {
    __shared__ int hist[256];
    __shared__ int offs[256];
    __shared__ int cur[256];
    __shared__ int gbase[256];
    __shared__ unsigned stage[CHUNK];
    __shared__ int nz;
    __shared__ int wsum[4];
    const int tid = threadIdx.x;
    const int base = blockIdx.x * CHUNK;
    const int cnt_c = min(CHUNK, E - base);

    if (tid == 0) nz = 0;
    hist[tid] = 0;
    cur[tid] = 0;
    __syncthreads();

    int found = 0;
    for (int j = tid; j < 1024; j += 256) {
        int e = base + j;
        if (e < E) found |= (ei[2 * e + 1] != 0);
    }
    if (found) atomicOr(&nz, 1);
    __syncthreads();
    const int is64 = (nz == 0);

    unsigned pr[16];
    #pragma unroll
    for (int j = 0; j < 16; ++j) {
        int e = base + j * 256 + tid;
        unsigned p = 0xFFFFFFFFu;
        if (e < E) {
            int s = is64 ? ei[2 * e] : ei[e];
            int d = is64 ? ei[2 * (E + e)] : ei[E + e];
            p = (unsigned)s | ((unsigned)d << 16);
            atomicAdd(&hist[d >> 8], 1);
        }
        pr[j] = p;
    }
    __syncthreads();

    // wave-level shfl scan of hist -> exclusive offs (1 barrier)
    int v = hist[tid];
    int incl = v;
    #pragma unroll
    for (int d = 1; d < 64; d <<= 1) {
        int t = __shfl_up(incl, d);
        if ((tid & 63) >= d) incl += t;
    }
    if ((tid & 63) == 63) wsum[tid >> 6] = incl;
    __syncthreads();
    int pre = 0;
    #pragma unroll
    for (int w = 0; w < 4; ++w)
        if (w < (tid >> 6)) pre += wsum[w];
    offs[tid] = pre + incl - v;
    if (tid < NB && v > 0) gbase[tid] = atomicAdd(&bcnt[tid], v);
    __syncthreads();

    #pragma unroll
    for (int j = 0; j < 16; ++j) {
        unsigned p = pr[j];
        if (p != 0xFFFFFFFFu) {
            int b = (int)(p >> 24);
            int pos = offs[b] + atomicAdd(&cur[b], 1);
            stage[pos] = p;
        }
    }
    __syncthreads();
    for (int i = tid; i < cnt_c; i += 256) {
        unsigned p = stage[i];
        int b = (int)(p >> 24);
        pairs[(size_t)b * BCAP + gbase[b] + (i - offs[b])] = p;
    }
}

// ---------------- per-bucket degree -> dis ----------------
__global__ __launch_bounds__(256) void degree_kernel(const unsigned* __restrict__ pairs,
                                                     const int* __restrict__ bcnt,
                                                     float* __restrict__ dis, int n) {
    __shared__ int hist[256];
    const int tid = threadIdx.x;
    const int bucket = blockIdx.x;
    hist[tid] = 0;
    __syncthreads();
    const int cb = bcnt[bucket];
    const unsigned* bp = pairs + (size_t)bucket * BCAP;
    for (int i = tid; i < cb; i += 256) {
        unsigned p = bp[i];
        atomicAdd(&hist[(p >> 16) & 255], 1);
    }
    __syncthreads();
    int node = bucket * 256 + tid;
    if (node < n) dis[node] = rsqrtf((float)hist[tid] + 1.0f);
}

// ---------------- W prep: transpose + split bf16 hi/lo, layout [c][k] ----------------
__global__ void wprep_kernel(const float* __restrict__ W,
                             short* __restrict__ wt_hi, short* __restrict__ wt_lo) {
    int idx = blockIdx.x * 256 + threadIdx.x;  // 0..65535
    int c = idx >> 10;
    int k = idx & 1023;
    float f = W[(size_t)k * NCLS + c];
    short hb = f2bf(f);
    wt_hi[idx] = hb;
    wt_lo[idx] = f2bf(f - bf2f(hb));
}

// ---------------- GEMM: 64-row tile, K-step 64, global_load_lds staging ----------------
__global__ __launch_bounds__(256) void gemm_mfma_kernel(const float* __restrict__ x,
                                                        const short* __restrict__ wt_hi,
                                                        const short* __restrict__ wt_lo,
                                                        float* __restrict__ h, int M) {
    __shared__ char smem[16 * 1040 + 8 * 1040 + 8 * 1040];
    char* As = smem;
    char* Bh = smem + 16 * 1040;
    char* Bl = smem + 24 * 1040;

    const int tid = threadIdx.x;
    const int wave = tid >> 6;
    const int lane = tid & 63;
    const int l15 = lane & 15, l4 = lane >> 4;
    const int row0 = blockIdx.x * 64;

    const float* agp[4];
    #pragma unroll
    for (int i = 0; i < 4; ++i) {
        int rg = row0 + (wave * 4 + i) * 4 + (lane >> 4);
        if (rg > M - 1) rg = M - 1;
        int g = (lane & 15) ^ (((lane >> 4) & 3) << 2);
        agp[i] = x + (size_t)rg * HIDDEN + g * 4;
    }
    const short* bhp[2];
    const short* blp[2];
    #pragma unroll
    for (int i = 0; i < 2; ++i) {
        int c = (wave * 2 + i) * 8 + (lane >> 3);
        int g = (lane & 7) ^ ((lane >> 3) & 7);
        bhp[i] = wt_hi + (size_t)c * HIDDEN + g * 8;
        blp[i] = wt_lo + (size_t)c * HIDDEN + g * 8;
    }

    f32x4 acc[4];
    #pragma unroll
    for (int nf = 0; nf < 4; ++nf) acc[nf] = (f32x4){0.f, 0.f, 0.f, 0.f};

    const int rt = wave * 16 + l15;
    const int r3 = rt & 3;
    char* arow = As + (rt >> 2) * 1040 + r3 * 256;

    for (int k0 = 0; k0 < HIDDEN; k0 += 64) {
        #pragma unroll
        for (int i = 0; i < 4; ++i)
            async_copy16(As + (wave * 4 + i) * 1040, agp[i] + k0);
        #pragma unroll
        for (int i = 0; i < 2; ++i) {
            async_copy16(Bh + (wave * 2 + i) * 1040, bhp[i] + k0);
            async_copy16(Bl + (wave * 2 + i) * 1040, blp[i] + k0);
        }
        __syncthreads();

        #pragma unroll
        for (int kk = 0; kk < 2; ++kk) {
            int js = (kk * 8 + l4 * 2) ^ (r3 << 2);
            f32x4 af0 = *reinterpret_cast<const f32x4*>(arow + js * 16);
            f32x4 af1 = *reinterpret_cast<const f32x4*>(arow + js * 16 + 16);
            short8 ah, al;
            #pragma unroll
            for (int j = 0; j < 4; ++j) {
                short hb = f2bf(af0[j]);
                ah[j] = hb;
                al[j] = f2bf(af0[j] - bf2f(hb));
                short hb2 = f2bf(af1[j]);
                ah[j + 4] = hb2;
                al[j + 4] = f2bf(af1[j] - bf2f(hb2));
            }
            #pragma unroll
            for (int nf = 0; nf < 4; ++nf) {
                int c = l15 + 16 * nf;
                int jb = (kk * 4 + l4) ^ (c & 7);
                size_t boff = (size_t)(c >> 3) * 1040 + (c & 7) * 128 + jb * 16;
                short8 bh = *reinterpret_cast<const short8*>(Bh + boff);
                short8 bl = *reinterpret_cast<const short8*>(Bl + boff);
                acc[nf] = __builtin_amdgcn_mfma_f32_16x16x32_bf16(ah, bh, acc[nf], 0, 0, 0);
                acc[nf] = __builtin_amdgcn_mfma_f32_16x16x32_bf16(al, bh, acc[nf], 0, 0, 0);
                acc[nf] = __builtin_amdgcn_mfma_f32_16x16x32_bf16(ah, bl, acc[nf], 0, 0, 0);
            }
        }
        __syncthreads();
    }

    #pragma unroll
    for (int j = 0; j < 4; ++j) {
        int r = row0 + wave * 16 + l4 * 4 + j;
        if (r < M) {
            #pragma unroll
            for (int nf = 0; nf < 4; ++nf) {
                h[(size_t)r * NCLS + l15 + 16 * nf] = acc[nf][j];
            }
        }
    }
}

// ---------------- fused agg v3: 4 edges per wave-load ----------------
// Block = 64 nodes (bucket quarter). lane = (g = l>>4, q = l&15); 16-lane
// group g gathers edge e+g via float4 (cols 4q..4q+3) -> 1KB / 4 edges per
// VMEM instruction. Group partials reduced via shfl_xor(16|32).
__global__ __launch_bounds__(256) void agg_kernel(const unsigned* __restrict__ pairs,
                                                  const int* __restrict__ bcnt,
                                                  const float* __restrict__ h,
                                                  const float* __restrict__ dis,
                                                  const float* __restrict__ bias,
                                                  float* __restrict__ out, int n) {
    __shared__ int hist[64];
    __shared__ int offs[64];
    __shared__ int cur[64];
    __shared__ unsigned short ssrc[GCAP];
    __shared__ float swt[GCAP];
    const int tid = threadIdx.x;
    const int bucket = blockIdx.x >> 2;
    const int split = blockIdx.x & 3;
    const int base_node = bucket * 256 + split * 64;
    if (base_node >= n) return;
    if (tid < 64) { hist[tid] = 0; cur[tid] = 0; }
    __syncthreads();
    const int cb = bcnt[bucket];
    const unsigned* bp = pairs + (size_t)bucket * BCAP;
    for (int i = tid; i < cb; i += 256) {
        unsigned p = bp[i];
        int loc = (int)((p >> 16) & 255u);
        if ((loc >> 6) == split) atomicAdd(&hist[loc & 63], 1);
    }
    __syncthreads();
    if (tid == 0) {
        int r = 0;
        #pragma unroll
        for (int k = 0; k < 64; ++k) { offs[k] = r; r += hist[k]; }
    }
    __syncthreads();
    for (int i = tid; i < cb; i += 256) {
        unsigned p = bp[i];
        int loc = (int)((p >> 16) & 255u);
        if ((loc >> 6) == split) {
            int ln = loc & 63;
            int pos = offs[ln] + atomicAdd(&cur[ln], 1);
            if (pos < GCAP) {
                int s = (int)(p & 0xFFFFu);
                ssrc[pos] = (unsigned short)s;
                swt[pos] = dis[s];
            }
        }
    }
    __syncthreads();

    const int wave = tid >> 6;
    const int lane = tid & 63;
    const int q = lane & 15;
    const int g = lane >> 4;
    const f32x4 bv = *reinterpret_cast<const f32x4*>(bias + q * 4);

    for (int t = 0; t < 16; ++t) {
        int ln = wave * 16 + t;
        int node = base_node + ln;
        if (node >= n) continue;
        int len = hist[ln];
        int e0 = offs[ln];
        float di = rsqrtf((float)len + 1.0f);

        f32x4 hs = *reinterpret_cast<const f32x4*>(h + (size_t)node * NCLS + q * 4);
        float selfw = (g == 0) ? di : 0.f;
        f32x4 a = {hs[0] * selfw, hs[1] * selfw, hs[2] * selfw, hs[3] * selfw};
        f32x4 a2 = {0.f, 0.f, 0.f, 0.f};

        for (int i = 0; i < len; i += 8) {
            int i1 = i + g;
            bool v1 = i1 < len;
            int s1 = v1 ? (int)ssrc[e0 + i1] : 0;
            float w1 = v1 ? swt[e0 + i1] : 0.f;
            f32x4 r1 = *reinterpret_cast<const f32x4*>(h + (size_t)s1 * NCLS + q * 4);
            if (i + 4 < len) {  // wave-uniform branch
                int i2 = i + 4 + g;
                bool v2 = i2 < len;
                int s2 = v2 ? (int)ssrc[e0 + i2] : 0;
                float w2 = v2 ? swt[e0 + i2] : 0.f;
                f32x4 r2 = *reinterpret_cast<const f32x4*>(h + (size_t)s2 * NCLS + q * 4);
                a2[0] += w2 * r2[0]; a2[1] += w2 * r2[1];
                a2[2] += w2 * r2[2]; a2[3] += w2 * r2[3];
            }
            a[0] += w1 * r1[0]; a[1] += w1 * r1[1];
            a[2] += w1 * r1[2]; a[3] += w1 * r1[3];
        }
        #pragma unroll
        for (int c = 0; c < 4; ++c) {
            float s = a[c] + a2[c];
            s += __shfl_xor(s, 16);
            s += __shfl_xor(s, 32);
            a[c] = s * di + bv[c];
        }
        float m = fmaxf(fmaxf(a[0], a[1]), fmaxf(a[2], a[3]));
        #pragma unroll
        for (int d = 1; d < 16; d <<= 1) m = fmaxf(m, __shfl_xor(m, d));
        f32x4 ex;
        #pragma unroll
        for (int c = 0; c < 4; ++c) ex[c] = __expf(a[c] - m);
        float sum = (ex[0] + ex[1]) + (ex[2] + ex[3]);
        #pragma unroll
        for (int d = 1; d < 16; d <<= 1) sum += __shfl_xor(sum, d);
        float inv = 1.f / sum;
        if (g == 0) {
            f32x4 o = {ex[0] * inv, ex[1] * inv, ex[2] * inv, ex[3] * inv};
            *reinterpret_cast<f32x4*>(out + (size_t)node * NCLS + q * 4) = o;
        }
    }
}

// ---------------- launcher ----------------
extern "C" void kernel_launch(void* const* d_in, const int* in_sizes, int n_in,
                              void* d_out, int out_size, void* d_ws, size_t ws_size,
                              hipStream_t stream) {
    const float* x    = (const float*)d_in[0];
    const int*   ei   = (const int*)d_in[1];
    const float* W    = (const float*)d_in[2];
    const float* bias = (const float*)d_in[3];
    float* out = (float*)d_out;

    const int n = in_sizes[0] / HIDDEN;   // 50000
    const int E = in_sizes[1] / 2;        // 1600000

    char* ws = (char*)d_ws;
    size_t off = 0;
    auto alloc = [&](size_t bytes) -> void* {
        void* p = (void*)(ws + off);
        off = (off + bytes + 255) & ~((size_t)255);
        return p;
    };
    int*      bcnt  = (int*)alloc((size_t)NB * 4);
    unsigned* pairs = (unsigned*)alloc((size_t)NB * BCAP * 4);
    float*    dis   = (float*)alloc((size_t)n * 4);
    float*    h     = (float*)alloc((size_t)n * NCLS * 4);
    short*    wt_hi = (short*)alloc((size_t)NCLS * HIDDEN * 2);
    short*    wt_lo = (short*)alloc((size_t)NCLS * HIDDEN * 2);
    (void)ws_size;

    hipMemsetAsync(bcnt, 0, (size_t)NB * 4, stream);

    bucket_kernel<<<(E + CHUNK - 1) / CHUNK, 256, 0, stream>>>(ei, pairs, bcnt, E);
    degree_kernel<<<NB, 256, 0, stream>>>(pairs, bcnt, dis, n);

    wprep_kernel<<<(NCLS * HIDDEN) / 256, 256, 0, stream>>>(W, wt_hi, wt_lo);
    gemm_mfma_kernel<<<(n + 63) / 64, 256, 0, stream>>>(x, wt_hi, wt_lo, h, n);
    agg_kernel<<<NB * 4, 256, 0, stream>>>(pairs, bcnt, h, dis, bias, out, n);
}

// Round 6
// 135.251 us; speedup vs baseline: 3.3393x; 1.2131x over previous
//
#include <hip/hip_runtime.h>
#include <hip/hip_bf16.h>
#include <hip/hip_fp16.h>
#include <math.h>

#define HIDDEN 1024
#define NCLS 64
#define NB 196          // node buckets: bucket = dst >> 8 (50000 -> 196)
#define BCAP 10240      // per-bucket capacity (mean 8192, max ~8550)
#define CHUNK 4096      // edges per bucket-role block
#define GCAP 4096       // per-64-node-group edge capacity (mean 2048, max ~2300)
#define SMEM_BYTES 33280  // max(gemm 32*1040, bucket ~21KB)

typedef __attribute__((ext_vector_type(8))) short short8;
typedef __attribute__((ext_vector_type(4))) float f32x4;
typedef __attribute__((ext_vector_type(8))) _Float16 half8;

__device__ __forceinline__ short f2bf(float f) {
    __hip_bfloat16 b = __float2bfloat16(f);
    return __builtin_bit_cast(short, b);
}
__device__ __forceinline__ float bf2f(short s) {
    unsigned u = ((unsigned)(unsigned short)s) << 16;
    return __builtin_bit_cast(float, u);
}

// async global->LDS, 16B per lane. LDS dest is wave-uniform base + lane*16.
__device__ __forceinline__ void async_copy16(void* lds, const void* g) {
    __builtin_amdgcn_global_load_lds(
        (const __attribute__((address_space(1))) unsigned int*)g,
        (__attribute__((address_space(3))) unsigned int*)lds, 16, 0, 0);
}

// ---------------- W prep: transpose + split bf16 hi/lo, layout [c][k] ----------------
__global__ void wprep_kernel(const float* __restrict__ W,
                             short* __restrict__ wt_hi, short* __restrict__ wt_lo) {
    int idx = blockIdx.x * 256 + threadIdx.x;  // 0..65535
    int c = idx >> 10;
    int k = idx & 1023;
    float f = W[(size_t)k * NCLS + c];
    short hb = f2bf(f);
    wt_hi[idx] = hb;
    wt_lo[idx] = f2bf(f - bf2f(hb));
}

// ================= bucket role (per-chunk scatter into dst-buckets) =================
__device__ void bucket_body(char* smem, const int* __restrict__ ei,
                            unsigned* __restrict__ pairs, int* __restrict__ bcnt,
                            int E, int bid) {
    int* hist = (int*)smem;
    int* offs = hist + 256;
    int* cur  = offs + 256;
    int* gbase = cur + 256;
    unsigned* stage = (unsigned*)(gbase + 256);
    int* nz = (int*)(stage + CHUNK);
    int* wsum = nz + 1;

    const int tid = threadIdx.x;
    const int base = bid * CHUNK;
    const int cnt_c = min(CHUNK, E - base);

    if (tid == 0) *nz = 0;
    hist[tid] = 0;
    cur[tid] = 0;
    __syncthreads();

    // per-block int64 detection from own chunk (1024 high-word samples)
    int found = 0;
    for (int j = tid; j < 1024; j += 256) {
        int e = base + j;
        if (e < E) found |= (ei[2 * e + 1] != 0);
    }
    if (found) atomicOr(nz, 1);
    __syncthreads();
    const int is64 = (*nz == 0);

    unsigned pr[16];
    #pragma unroll
    for (int j = 0; j < 16; ++j) {
        int e = base + j * 256 + tid;
        unsigned p = 0xFFFFFFFFu;
        if (e < E) {
            int s = is64 ? ei[2 * e] : ei[e];
            int d = is64 ? ei[2 * (E + e)] : ei[E + e];
            p = (unsigned)s | ((unsigned)d << 16);
            atomicAdd(&hist[d >> 8], 1);
        }
        pr[j] = p;
    }
    __syncthreads();

    // wave shfl scan of hist -> exclusive offs
    int v = hist[tid];
    int incl = v;
    #pragma unroll
    for (int d = 1; d < 64; d <<= 1) {
        int t = __shfl_up(incl, d);
        if ((tid & 63) >= d) incl += t;
    }
    if ((tid & 63) == 63) wsum[tid >> 6] = incl;
    __syncthreads();
    int pre = 0;
    #pragma unroll
    for (int w = 0; w < 4; ++w)
        if (w < (tid >> 6)) pre += wsum[w];
    offs[tid] = pre + incl - v;
    if (tid < NB && v > 0) gbase[tid] = atomicAdd(&bcnt[tid], v);
    __syncthreads();

    #pragma unroll
    for (int j = 0; j < 16; ++j) {
        unsigned p = pr[j];
        if (p != 0xFFFFFFFFu) {
            int b = (int)(p >> 24);
            int pos = offs[b] + atomicAdd(&cur[b], 1);
            stage[pos] = p;
        }
    }
    __syncthreads();
    for (int i = tid; i < cnt_c; i += 256) {
        unsigned p = stage[i];
        int b = (int)(p >> 24);
        pairs[(size_t)b * BCAP + gbase[b] + (i - offs[b])] = p;
    }
}

// ================= gemm role: h16 = fp16(x @ W), split-bf16 MFMA =================
__device__ void gemm_body(char* smem, const float* __restrict__ x,
                          const short* __restrict__ wt_hi, const short* __restrict__ wt_lo,
                          _Float16* __restrict__ h16, int M, int bid) {
    char* As = smem;
    char* Bh = smem + 16 * 1040;
    char* Bl = smem + 24 * 1040;

    const int tid = threadIdx.x;
    const int wave = tid >> 6;
    const int lane = tid & 63;
    const int l15 = lane & 15, l4 = lane >> 4;
    const int row0 = bid * 64;

    const float* agp[4];
    #pragma unroll
    for (int i = 0; i < 4; ++i) {
        int rg = row0 + (wave * 4 + i) * 4 + (lane >> 4);
        if (rg > M - 1) rg = M - 1;
        int g = (lane & 15) ^ (((lane >> 4) & 3) << 2);
        agp[i] = x + (size_t)rg * HIDDEN + g * 4;
    }
    const short* bhp[2];
    const short* blp[2];
    #pragma unroll
    for (int i = 0; i < 2; ++i) {
        int c = (wave * 2 + i) * 8 + (lane >> 3);
        int g = (lane & 7) ^ ((lane >> 3) & 7);
        bhp[i] = wt_hi + (size_t)c * HIDDEN + g * 8;
        blp[i] = wt_lo + (size_t)c * HIDDEN + g * 8;
    }

    f32x4 acc[4];
    #pragma unroll
    for (int nf = 0; nf < 4; ++nf) acc[nf] = (f32x4){0.f, 0.f, 0.f, 0.f};

    const int rt = wave * 16 + l15;
    const int r3 = rt & 3;
    char* arow = As + (rt >> 2) * 1040 + r3 * 256;

    for (int k0 = 0; k0 < HIDDEN; k0 += 64) {
        #pragma unroll
        for (int i = 0; i < 4; ++i)
            async_copy16(As + (wave * 4 + i) * 1040, agp[i] + k0);
        #pragma unroll
        for (int i = 0; i < 2; ++i) {
            async_copy16(Bh + (wave * 2 + i) * 1040, bhp[i] + k0);
            async_copy16(Bl + (wave * 2 + i) * 1040, blp[i] + k0);
        }
        __syncthreads();

        #pragma unroll
        for (int kk = 0; kk < 2; ++kk) {
            int js = (kk * 8 + l4 * 2) ^ (r3 << 2);
            f32x4 af0 = *reinterpret_cast<const f32x4*>(arow + js * 16);
            f32x4 af1 = *reinterpret_cast<const f32x4*>(arow + js * 16 + 16);
            short8 ah, al;
            #pragma unroll
            for (int j = 0; j < 4; ++j) {
                short hb = f2bf(af0[j]);
                ah[j] = hb;
                al[j] = f2bf(af0[j] - bf2f(hb));
                short hb2 = f2bf(af1[j]);
                ah[j + 4] = hb2;
                al[j + 4] = f2bf(af1[j] - bf2f(hb2));
            }
            #pragma unroll
            for (int nf = 0; nf < 4; ++nf) {
                int c = l15 + 16 * nf;
                int jb = (kk * 4 + l4) ^ (c & 7);
                size_t boff = (size_t)(c >> 3) * 1040 + (c & 7) * 128 + jb * 16;
                short8 bh = *reinterpret_cast<const short8*>(Bh + boff);
                short8 bl = *reinterpret_cast<const short8*>(Bl + boff);
                acc[nf] = __builtin_amdgcn_mfma_f32_16x16x32_bf16(ah, bh, acc[nf], 0, 0, 0);
                acc[nf] = __builtin_amdgcn_mfma_f32_16x16x32_bf16(al, bh, acc[nf], 0, 0, 0);
                acc[nf] = __builtin_amdgcn_mfma_f32_16x16x32_bf16(ah, bl, acc[nf], 0, 0, 0);
            }
        }
        __syncthreads();
    }

    #pragma unroll
    for (int j = 0; j < 4; ++j) {
        int r = row0 + wave * 16 + l4 * 4 + j;
        if (r < M) {
            #pragma unroll
            for (int nf = 0; nf < 4; ++nf) {
                h16[(size_t)r * NCLS + l15 + 16 * nf] = (_Float16)acc[nf][j];
            }
        }
    }
}

// ================= fat kernel: gemm-role blocks || bucket-role blocks =================
__global__ __launch_bounds__(256) void fat_kernel(const float* __restrict__ x,
                                                  const short* __restrict__ wt_hi,
                                                  const short* __restrict__ wt_lo,
                                                  _Float16* __restrict__ h16, int M,
                                                  const int* __restrict__ ei,
                                                  unsigned* __restrict__ pairs,
                                                  int* __restrict__ bcnt, int E,
                                                  int nGemmBlocks) {
    __shared__ __align__(16) char smem[SMEM_BYTES];
    if ((int)blockIdx.x < nGemmBlocks)
        gemm_body(smem, x, wt_hi, wt_lo, h16, M, blockIdx.x);
    else
        bucket_body(smem, ei, pairs, bcnt, E, blockIdx.x - nGemmBlocks);
}

// ---------------- per-bucket degree -> dis ----------------
__global__ __launch_bounds__(256) void degree_kernel(const unsigned* __restrict__ pairs,
                                                     const int* __restrict__ bcnt,
                                                     float* __restrict__ dis, int n) {
    __shared__ int hist[256];
    const int tid = threadIdx.x;
    const int bucket = blockIdx.x;
    hist[tid] = 0;
    __syncthreads();
    const int cb = bcnt[bucket];
    const unsigned* bp = pairs + (size_t)bucket * BCAP;
    for (int i = tid; i < cb; i += 256) {
        unsigned p = bp[i];
        atomicAdd(&hist[(p >> 16) & 255], 1);
    }
    __syncthreads();
    int node = bucket * 256 + tid;
    if (node < n) dis[node] = rsqrtf((float)hist[tid] + 1.0f);
}

// ---------------- fused agg v4: 8 edges per wave-load (half8 gathers) ----------------
// Block = 64 nodes. lane = (g = l>>3 in 0..7, q = l&7); group g gathers edge
// e+g, lane loads half8 (16B) of cols 8q..8q+7 -> 8 edges / wave instruction.
__global__ __launch_bounds__(256) void agg_kernel(const unsigned* __restrict__ pairs,
                                                  const int* __restrict__ bcnt,
                                                  const _Float16* __restrict__ h16,
                                                  const float* __restrict__ dis,
                                                  const float* __restrict__ bias,
                                                  float* __restrict__ out, int n) {
    __shared__ int hist[64];
    __shared__ int offs[64];
    __shared__ int cur[64];
    __shared__ unsigned short ssrc[GCAP];
    __shared__ float swt[GCAP];
    const int tid = threadIdx.x;
    const int bucket = blockIdx.x >> 2;
    const int split = blockIdx.x & 3;
    const int base_node = bucket * 256 + split * 64;
    if (base_node >= n) return;
    if (tid < 64) { hist[tid] = 0; cur[tid] = 0; }
    __syncthreads();
    const int cb = bcnt[bucket];
    const unsigned* bp = pairs + (size_t)bucket * BCAP;
    for (int i = tid; i < cb; i += 256) {
        unsigned p = bp[i];
        int loc = (int)((p >> 16) & 255u);
        if ((loc >> 6) == split) atomicAdd(&hist[loc & 63], 1);
    }
    __syncthreads();
    if (tid == 0) {
        int r = 0;
        #pragma unroll
        for (int k = 0; k < 64; ++k) { offs[k] = r; r += hist[k]; }
    }
    __syncthreads();
    for (int i = tid; i < cb; i += 256) {
        unsigned p = bp[i];
        int loc = (int)((p >> 16) & 255u);
        if ((loc >> 6) == split) {
            int ln = loc & 63;
            int pos = offs[ln] + atomicAdd(&cur[ln], 1);
            if (pos < GCAP) {
                int s = (int)(p & 0xFFFFu);
                ssrc[pos] = (unsigned short)s;
                swt[pos] = dis[s];
            }
        }
    }
    __syncthreads();

    const int wave = tid >> 6;
    const int lane = tid & 63;
    const int q = lane & 7;    // col-octet owner
    const int g = lane >> 3;   // edge group 0..7
    float bv[8];
    #pragma unroll
    for (int c = 0; c < 8; ++c) bv[c] = bias[q * 8 + c];

    for (int t = 0; t < 16; ++t) {
        int ln = wave * 16 + t;
        int node = base_node + ln;
        if (node >= n) continue;
        int len = hist[ln];
        int e0 = offs[ln];
        float di = rsqrtf((float)len + 1.0f);

        half8 hs = *reinterpret_cast<const half8*>(h16 + (size_t)node * NCLS + q * 8);
        float selfw = (g == 0) ? di : 0.f;
        float a[8], a2[8];
        #pragma unroll
        for (int c = 0; c < 8; ++c) { a[c] = (float)hs[c] * selfw; a2[c] = 0.f; }

        for (int i = 0; i < len; i += 16) {
            int i1 = i + g;
            bool v1 = i1 < len;
            int s1 = v1 ? (int)ssrc[e0 + i1] : 0;
            float w1 = v1 ? swt[e0 + i1] : 0.f;
            half8 r1 = *reinterpret_cast<const half8*>(h16 + (size_t)s1 * NCLS + q * 8);
            if (i + 8 < len) {  // wave-uniform
                int i2 = i + 8 + g;
                bool v2 = i2 < len;
                int s2 = v2 ? (int)ssrc[e0 + i2] : 0;
                float w2 = v2 ? swt[e0 + i2] : 0.f;
                half8 r2 = *reinterpret_cast<const half8*>(h16 + (size_t)s2 * NCLS + q * 8);
                #pragma unroll
                for (int c = 0; c < 8; ++c) a2[c] += w2 * (float)r2[c];
            }
            #pragma unroll
            for (int c = 0; c < 8; ++c) a[c] += w1 * (float)r1[c];
        }
        // reduce across the 8 edge-groups (lanes differing in bits 3..5)
        #pragma unroll
        for (int c = 0; c < 8; ++c) {
            float s = a[c] + a2[c];
            s += __shfl_xor(s, 8);
            s += __shfl_xor(s, 16);
            s += __shfl_xor(s, 32);
            a[c] = s * di + bv[c];
        }
        // softmax over 64 cols: in-lane 8 + across the 8 q-lanes (bits 0..2)
        float m = a[0];
        #pragma unroll
        for (int c = 1; c < 8; ++c) m = fmaxf(m, a[c]);
        #pragma unroll
        for (int d = 1; d < 8; d <<= 1) m = fmaxf(m, __shfl_xor(m, d));
        float ex[8], sum = 0.f;
        #pragma unroll
        for (int c = 0; c < 8; ++c) { ex[c] = __expf(a[c] - m); sum += ex[c]; }
        #pragma unroll
        for (int d = 1; d < 8; d <<= 1) sum += __shfl_xor(sum, d);
        float inv = 1.f / sum;
        if (g == 0) {
            f32x4 o0 = {ex[0] * inv, ex[1] * inv, ex[2] * inv, ex[3] * inv};
            f32x4 o1 = {ex[4] * inv, ex[5] * inv, ex[6] * inv, ex[7] * inv};
            *reinterpret_cast<f32x4*>(out + (size_t)node * NCLS + q * 8) = o0;
            *reinterpret_cast<f32x4*>(out + (size_t)node * NCLS + q * 8 + 4) = o1;
        }
    }
}

// ---------------- launcher ----------------
extern "C" void kernel_launch(void* const* d_in, const int* in_sizes, int n_in,
                              void* d_out, int out_size, void* d_ws, size_t ws_size,
                              hipStream_t stream) {
    const float* x    = (const float*)d_in[0];
    const int*   ei   = (const int*)d_in[1];
    const float* W    = (const float*)d_in[2];
    const float* bias = (const float*)d_in[3];
    float* out = (float*)d_out;

    const int n = in_sizes[0] / HIDDEN;   // 50000
    const int E = in_sizes[1] / 2;        // 1600000

    char* ws = (char*)d_ws;
    size_t off = 0;
    auto alloc = [&](size_t bytes) -> void* {
        void* p = (void*)(ws + off);
        off = (off + bytes + 255) & ~((size_t)255);
        return p;
    };
    int*      bcnt  = (int*)alloc((size_t)NB * 4);
    unsigned* pairs = (unsigned*)alloc((size_t)NB * BCAP * 4);
    float*    dis   = (float*)alloc((size_t)n * 4);
    _Float16* h16   = (_Float16*)alloc((size_t)n * NCLS * 2);
    short*    wt_hi = (short*)alloc((size_t)NCLS * HIDDEN * 2);
    short*    wt_lo = (short*)alloc((size_t)NCLS * HIDDEN * 2);
    (void)ws_size;

    hipMemsetAsync(bcnt, 0, (size_t)NB * 4, stream);

    wprep_kernel<<<(NCLS * HIDDEN) / 256, 256, 0, stream>>>(W, wt_hi, wt_lo);

    const int nGemmBlocks = (n + 63) / 64;             // 782
    const int nBucketBlocks = (E + CHUNK - 1) / CHUNK; // 391
    fat_kernel<<<nGemmBlocks + nBucketBlocks, 256, 0, stream>>>(
        x, wt_hi, wt_lo, h16, n, ei, pairs, bcnt, E, nGemmBlocks);

    degree_kernel<<<NB, 256, 0, stream>>>(pairs, bcnt, dis, n);
    agg_kernel<<<NB * 4, 256, 0, stream>>>(pairs, bcnt, h16, dis, bias, out, n);
}